// Round 6
// baseline (67.608 us; speedup 1.0000x reference)
//
#include <hip/hip_runtime.h>

#define N_POINTS 204800
#define N_GT 256
#define BLOCK 512            // 8 waves
#define PTS_PER_BLOCK 512    // 64 lanes x 8 points/thread
#define GRID (N_POINTS / PTS_PER_BLOCK)  // 400 blocks

typedef float v2f __attribute__((ext_vector_type(2)));

// Packed-FP32 FMA: d = a*b + c on both halves (one VALU slot for 2 FMAs).
__device__ __forceinline__ v2f pk_fma(v2f a, v2f b, v2f c) {
  v2f d;
  asm("v_pk_fma_f32 %0, %1, %2, %3" : "=v"(d) : "v"(a), "v"(b), "v"(c));
  return d;
}

// Math (R1-R5): per box, centerness^2 = max(fx,0)*fy under a >=0 max-reduction
// (one-clamp trick), fx/fy quadratics in px/py with division folded into
// coefficients; sqrt hoisted out of the 256-box max.
// R6: pair the x/y quadratics in v_pk_fma_f32 (CDNA packed fp32): coef layout
// per box = {a2x,a2y, a1x,a1y, a0x,a0y}, point packed (X,Y) -> 2 pk-FMA per
// box-point instead of 4 FMAs. 4.5 issue-slots/box-point (was 6.5).
// Structure from R5 (validated by the R4->R5 delta matching the VALU-op cut):
// 400 blocks x 8 waves, 32-box chunk per wave, 8 pts/thread, 2 blocks/CU via
// __launch_bounds__(512,4), broadcast ds_read_b128 coef reads, LDS epilogue.
__global__ __launch_bounds__(BLOCK, 4) void centerness_kernel(
    const float* __restrict__ points, const float* __restrict__ gt,
    float* __restrict__ out) {
  __shared__ float scoef[6 * N_GT];   // 24B/box, x/y-interleaved (6144 B)
  __shared__ float spart[8 * 512];    // per-wave partial maxes (16384 B)

  const int t = threadIdx.x;
  const int lane = t & 63;
  const int w = t >> 6;  // wave id = 32-box chunk id

  // --- issue point loads first (independent of staging) ---
  const int base4 = blockIdx.x * 256;  // float4 index; each f4 = 2 points
  const float4* p4 = (const float4*)points;
  float4 pA = p4[base4 + lane];
  float4 pB = p4[base4 + 64 + lane];
  float4 pC = p4[base4 + 128 + lane];
  float4 pD = p4[base4 + 192 + lane];

  // --- stage coefficients: one box per thread (threads 0..255) ---
  if (t < N_GT) {
    float4 b = ((const float4*)gt)[t];  // x1,y1,x2,y2
    float iw = 1.0f / (b.z - b.x);
    float ih = 1.0f / (b.w - b.y);
    float* c = &scoef[6 * t];
    c[0] = -iw;              c[1] = -ih;
    c[2] = (b.x + b.z) * iw; c[3] = (b.y + b.w) * ih;
    c[4] = -(b.x * b.z) * iw; c[5] = -(b.y * b.w) * ih;
  }
  __syncthreads();

  // packed points (X,Y) per point
  v2f P[8];
  P[0] = (v2f){pA.x, pA.y}; P[1] = (v2f){pA.z, pA.w};
  P[2] = (v2f){pB.x, pB.y}; P[3] = (v2f){pB.z, pB.w};
  P[4] = (v2f){pC.x, pC.y}; P[5] = (v2f){pC.z, pC.w};
  P[6] = (v2f){pD.x, pD.y}; P[7] = (v2f){pD.z, pD.w};

  float acc[8];
#pragma unroll
  for (int p = 0; p < 8; ++p) acc[p] = 0.0f;

  // --- 32-box chunk: 8 groups of 4 boxes, 6 uniform (broadcast) b128 reads ---
  const float4* c4 = (const float4*)scoef;
  const int cbase = w * 48;  // 32 boxes * 6 floats / 4

#pragma unroll 1
  for (int g = 0; g < 8; ++g) {
    float4 q0 = c4[cbase + 6 * g + 0];
    float4 q1 = c4[cbase + 6 * g + 1];
    float4 q2 = c4[cbase + 6 * g + 2];
    float4 q3 = c4[cbase + 6 * g + 3];
    float4 q4 = c4[cbase + 6 * g + 4];
    float4 q5 = c4[cbase + 6 * g + 5];
    // box0: a2=(q0.x,q0.y) a1=(q0.z,q0.w) a0=(q1.x,q1.y)
    // box1: a2=(q1.z,q1.w) a1=(q2.x,q2.y) a0=(q2.z,q2.w)
    // box2: a2=(q3.x,q3.y) a1=(q3.z,q3.w) a0=(q4.x,q4.y)
    // box3: a2=(q4.z,q4.w) a1=(q5.x,q5.y) a0=(q5.z,q5.w)
    v2f c0a = (v2f){q0.x, q0.y}, c0b = (v2f){q0.z, q0.w}, c0c = (v2f){q1.x, q1.y};
    v2f c1a = (v2f){q1.z, q1.w}, c1b = (v2f){q2.x, q2.y}, c1c = (v2f){q2.z, q2.w};
    v2f c2a = (v2f){q3.x, q3.y}, c2b = (v2f){q3.z, q3.w}, c2c = (v2f){q4.x, q4.y};
    v2f c3a = (v2f){q4.z, q4.w}, c3b = (v2f){q5.x, q5.y}, c3c = (v2f){q5.z, q5.w};

#pragma unroll
    for (int p = 0; p < 8; ++p) {
      v2f r0 = pk_fma(pk_fma(c0a, P[p], c0b), P[p], c0c);  // (fx,fy) box0
      v2f r1 = pk_fma(pk_fma(c1a, P[p], c1b), P[p], c1c);  // box1
      float v0 = fmaxf(r0.x, 0.f) * r0.y;
      float v1 = fmaxf(r1.x, 0.f) * r1.y;
      acc[p] = fmaxf(fmaxf(acc[p], v0), v1);  // -> v_max3_f32
      v2f r2 = pk_fma(pk_fma(c2a, P[p], c2b), P[p], c2c);  // box2
      v2f r3 = pk_fma(pk_fma(c3a, P[p], c3b), P[p], c3c);  // box3
      float v2 = fmaxf(r2.x, 0.f) * r2.y;
      float v3 = fmaxf(r3.x, 0.f) * r3.y;
      acc[p] = fmaxf(fmaxf(acc[p], v2), v3);
    }
  }

  // --- partials to LDS: spart[w][local point id] ---
#pragma unroll
  for (int p = 0; p < 8; p += 2) {
    float2* sp2 = (float2*)&spart[w * 512 + 128 * (p >> 1)];
    sp2[lane] = make_float2(acc[p], acc[p + 1]);
  }
  __syncthreads();

  // --- all 8 waves reduce: thread t owns local point t (conflict-free) ---
  float m = spart[t];
#pragma unroll
  for (int i = 1; i < 8; ++i) m = fmaxf(m, spart[i * 512 + t]);
  out[blockIdx.x * PTS_PER_BLOCK + t] = sqrtf(m);
}

extern "C" void kernel_launch(void* const* d_in, const int* in_sizes, int n_in,
                              void* d_out, int out_size, void* d_ws, size_t ws_size,
                              hipStream_t stream) {
  const float* points = (const float*)d_in[0];     // (204800, 2)
  const float* gt_bboxes = (const float*)d_in[1];  // (256, 4)
  // d_in[2] strides: unused by the reference output.
  float* out = (float*)d_out;                      // (204800,)

  centerness_kernel<<<GRID, BLOCK, 0, stream>>>(points, gt_bboxes, out);
}

// Round 7
// 65.717 us; speedup vs baseline: 1.0288x; 1.0288x over previous
//
#include <hip/hip_runtime.h>

#define N_POINTS 204800
#define N_GT 256
#define BLOCK 512            // 8 waves
#define PTS_PER_BLOCK 512    // 64 lanes x 8 points/thread
#define GRID (N_POINTS / PTS_PER_BLOCK)  // 400 blocks

typedef float v2f __attribute__((ext_vector_type(2)));

// Packed fp32 FMA expressed as native vector IR -> llvm.fma.v2f32 -> the
// backend's v_pk_fma_f32 pattern (gfx90a+). NO inline asm: R6 showed asm-based
// pk_fma regressed (register-marshalling movs / scheduling barrier); letting
// the allocator pick subregister halves of ds_read_b128 results should make
// packing mov-free.
__device__ __forceinline__ v2f pk_fma(v2f a, v2f b, v2f c) {
  return __builtin_elementwise_fma(a, b, c);
}
__device__ __forceinline__ v2f lohalf(float4 q) { return (v2f){q.x, q.y}; }
__device__ __forceinline__ v2f hihalf(float4 q) { return (v2f){q.z, q.w}; }

// Math (R1-R6): per box, centerness^2 = max(fx,0)*fy under a >=0 max-reduction
// (one-clamp), fx/fy are quadratics in px/py with the l+r division folded into
// coefficients; sqrt hoisted out of the 256-box max.
// Coefficient layout (24B/box, x/y interleaved) makes every (a2x,a2y) etc. a
// natural even-aligned half of a ds_read_b128 float4.
// Structure from R5 (best measured): 400 blocks x 8 waves, 32-box chunk per
// wave, 8 pts/thread, 2 blocks/CU via __launch_bounds__(512,4), broadcast
// ds_read_b128 coef reads, all-wave LDS epilogue reduction.
__global__ __launch_bounds__(BLOCK, 4) void centerness_kernel(
    const float* __restrict__ points, const float* __restrict__ gt,
    float* __restrict__ out) {
  __shared__ float scoef[6 * N_GT];   // 24B/box, x/y-interleaved (6144 B)
  __shared__ float spart[8 * 512];    // per-wave partial maxes (16384 B)

  const int t = threadIdx.x;
  const int lane = t & 63;
  const int w = t >> 6;  // wave id = 32-box chunk id

  // --- issue point loads first (independent of staging) ---
  const int base4 = blockIdx.x * 256;  // float4 index; each f4 = 2 points
  const float4* p4 = (const float4*)points;
  float4 pA = p4[base4 + lane];
  float4 pB = p4[base4 + 64 + lane];
  float4 pC = p4[base4 + 128 + lane];
  float4 pD = p4[base4 + 192 + lane];

  // --- stage coefficients: one box per thread (threads 0..255) ---
  if (t < N_GT) {
    float4 b = ((const float4*)gt)[t];  // x1,y1,x2,y2
    float iw = 1.0f / (b.z - b.x);
    float ih = 1.0f / (b.w - b.y);
    float* c = &scoef[6 * t];
    c[0] = -iw;               c[1] = -ih;
    c[2] = (b.x + b.z) * iw;  c[3] = (b.y + b.w) * ih;
    c[4] = -(b.x * b.z) * iw; c[5] = -(b.y * b.w) * ih;
  }
  __syncthreads();

  // packed points (X,Y); halves of loaded float4s (subregister extracts)
  v2f P[8];
  P[0] = lohalf(pA); P[1] = hihalf(pA);
  P[2] = lohalf(pB); P[3] = hihalf(pB);
  P[4] = lohalf(pC); P[5] = hihalf(pC);
  P[6] = lohalf(pD); P[7] = hihalf(pD);

  float acc[8];
#pragma unroll
  for (int p = 0; p < 8; ++p) acc[p] = 0.0f;

  // --- 32-box chunk: 8 groups of 4 boxes, 6 uniform (broadcast) b128 reads ---
  const float4* c4 = (const float4*)scoef;
  const int cbase = w * 48;  // 32 boxes * 6 floats / 4

#pragma unroll 1
  for (int g = 0; g < 8; ++g) {
    float4 q0 = c4[cbase + 6 * g + 0];
    float4 q1 = c4[cbase + 6 * g + 1];
    float4 q2 = c4[cbase + 6 * g + 2];
    float4 q3 = c4[cbase + 6 * g + 3];
    float4 q4 = c4[cbase + 6 * g + 4];
    float4 q5 = c4[cbase + 6 * g + 5];
    // box0: a2=lo(q0) a1=hi(q0) a0=lo(q1)
    // box1: a2=hi(q1) a1=lo(q2) a0=hi(q2)
    // box2: a2=lo(q3) a1=hi(q3) a0=lo(q4)
    // box3: a2=hi(q4) a1=lo(q5) a0=hi(q5)
    v2f c0a = lohalf(q0), c0b = hihalf(q0), c0c = lohalf(q1);
    v2f c1a = hihalf(q1), c1b = lohalf(q2), c1c = hihalf(q2);
    v2f c2a = lohalf(q3), c2b = hihalf(q3), c2c = lohalf(q4);
    v2f c3a = hihalf(q4), c3b = lohalf(q5), c3c = hihalf(q5);

#pragma unroll
    for (int p = 0; p < 8; ++p) {
      v2f Pp = P[p];
      v2f r0 = pk_fma(pk_fma(c0a, Pp, c0b), Pp, c0c);  // (fx,fy) box0
      v2f r1 = pk_fma(pk_fma(c1a, Pp, c1b), Pp, c1c);  // box1
      float v0 = fmaxf(r0.x, 0.f) * r0.y;
      float v1 = fmaxf(r1.x, 0.f) * r1.y;
      acc[p] = fmaxf(fmaxf(acc[p], v0), v1);  // -> v_max3_f32
      v2f r2 = pk_fma(pk_fma(c2a, Pp, c2b), Pp, c2c);  // box2
      v2f r3 = pk_fma(pk_fma(c3a, Pp, c3b), Pp, c3c);  // box3
      float v2 = fmaxf(r2.x, 0.f) * r2.y;
      float v3 = fmaxf(r3.x, 0.f) * r3.y;
      acc[p] = fmaxf(fmaxf(acc[p], v2), v3);
    }
  }

  // --- partials to LDS: spart[w][local point id] ---
#pragma unroll
  for (int p = 0; p < 8; p += 2) {
    float2* sp2 = (float2*)&spart[w * 512 + 128 * (p >> 1)];
    sp2[lane] = make_float2(acc[p], acc[p + 1]);
  }
  __syncthreads();

  // --- all 8 waves reduce: thread t owns local point t (conflict-free) ---
  float m = spart[t];
#pragma unroll
  for (int i = 1; i < 8; ++i) m = fmaxf(m, spart[i * 512 + t]);
  out[blockIdx.x * PTS_PER_BLOCK + t] = sqrtf(m);
}

extern "C" void kernel_launch(void* const* d_in, const int* in_sizes, int n_in,
                              void* d_out, int out_size, void* d_ws, size_t ws_size,
                              hipStream_t stream) {
  const float* points = (const float*)d_in[0];     // (204800, 2)
  const float* gt_bboxes = (const float*)d_in[1];  // (256, 4)
  // d_in[2] strides: unused by the reference output.
  float* out = (float*)d_out;                      // (204800,)

  centerness_kernel<<<GRID, BLOCK, 0, stream>>>(points, gt_bboxes, out);
}